// Round 1
// baseline (211.511 us; speedup 1.0000x reference)
//
#include <hip/hip_runtime.h>
#include <hip/hip_bf16.h>

// out[512, 65536] = inputs[512,256] @ features[65536,256]^T  (fp32 in/out)
//
// v2: A (inputs) pre-converted to bf16 in workspace by a tiny kernel, then
// staged into LDS via async global_load_lds_dwordx4 (zero VALU). B (features)
// keeps fused fp32->bf16 conversion during reg-staging. MFMA operands swapped
// so each lane's accumulator is contiguous in N -> f32x4 epilogue stores.

#define M_DIM 512
#define N_DIM 65536
#define K_DIM 256
#define BM 128
#define BN 128
#define BK 64
#define LDKB (BK + 8)   // Bs pad: breaks 128B row stride (2-way conflict = free)

typedef __bf16 bf16x8 __attribute__((ext_vector_type(8)));
typedef float f32x4 __attribute__((ext_vector_type(4)));

// ---- kernel 1: inputs [512][256] fp32 -> bf16 workspace (0.25 MB) ----
__global__ __launch_bounds__(256) void cvt_inputs(const float* __restrict__ A,
                                                  __bf16* __restrict__ Aw) {
    const int t = blockIdx.x * 256 + threadIdx.x;   // 16384 threads x 8 elems
    const float* src = A + (size_t)t * 8;
    f32x4 v0 = *(const f32x4*)src;
    f32x4 v1 = *(const f32x4*)(src + 4);
    bf16x8 h;
    h[0] = (__bf16)v0[0]; h[1] = (__bf16)v0[1];
    h[2] = (__bf16)v0[2]; h[3] = (__bf16)v0[3];
    h[4] = (__bf16)v1[0]; h[5] = (__bf16)v1[1];
    h[6] = (__bf16)v1[2]; h[7] = (__bf16)v1[3];
    *(bf16x8*)(Aw + (size_t)t * 8) = h;
}

// async 16B global->LDS (wave-uniform LDS base + lane*16; global addr per-lane)
static __device__ __forceinline__ void gload_lds16(const __bf16* g, __bf16* l) {
    __builtin_amdgcn_global_load_lds(
        (const __attribute__((address_space(1))) void*)g,
        (__attribute__((address_space(3))) void*)l, 16, 0, 0);
}

// ---- kernel 2: bf16 MFMA GEMM, C = A * B^T ----
__global__ __launch_bounds__(256, 2) void hm_gemm_bt(
    const __bf16* __restrict__ Aw,  // [512][256] bf16 (workspace)
    const float*  __restrict__ B,   // features [65536][256] fp32
    float* __restrict__ C)          // out [512][65536] fp32
{
    __shared__ __align__(16) __bf16 As[BM * BK];    // 16 KB, LINEAR (gload_lds dest)
    __shared__ __align__(16) __bf16 Bs[BN * LDKB]; // 18 KB, padded (reg-staged)

    const int tid  = threadIdx.x;
    const int lane = tid & 63;
    const int wave = tid >> 6;            // 4 waves, 2x2 grid of 64x64 subtiles
    const int wm   = (wave >> 1) * 64;
    const int wn   = (wave & 1) * 64;

    const int m0 = blockIdx.x * BM;       // grid.x = 4 (M-tiles adjacent: L2 reuse of B)
    const int n0 = blockIdx.y * BN;       // grid.y = 512

    // A staging geometry: chunk c = r*4+wave covers rows 8c..8c+7 (128B/row).
    // lane l -> LDS byte l*16 -> row 8c + (l>>3), k-elems (l&7)*8.
    const int arow = lane >> 3;
    const int akc  = (lane & 7) * 8;

    f32x4 acc[4][4];
    #pragma unroll
    for (int i = 0; i < 4; ++i)
        #pragma unroll
        for (int j = 0; j < 4; ++j)
            acc[i][j] = f32x4{0.f, 0.f, 0.f, 0.f};

    // MFMA 16x16x32 bf16 mapping (verified by current passing kernel):
    //   first operand's row-index -> D.row=(lane>>4)*4+reg; second's -> D.col=lane&15
    // We call mfma(b_frag, a_frag, acc): D.row -> n (contiguous per lane!), D.col -> m.
    const int lrow = lane & 15;
    const int lk   = (lane >> 4) * 8;

    for (int k0 = 0; k0 < K_DIM; k0 += BK) {
        // ---- A tile: 128x64 bf16 via async global_load_lds (16 wave-insts total)
        #pragma unroll
        for (int r = 0; r < 4; ++r) {
            const int chunk = r * 4 + wave;             // wave-uniform
            const int row   = chunk * 8 + arow;
            gload_lds16(Aw + (size_t)(m0 + row) * K_DIM + k0 + akc,
                        As + chunk * 512);              // 512 bf16 = 1024 B / chunk
        }
        // ---- B tile: 128x64 fp32 -> bf16, reg-staged (overlaps A's DMA)
        #pragma unroll
        for (int i = 0; i < 4; ++i) {
            const int c   = i * 256 + tid;      // 0..1023
            const int row = c >> 3;             // 8 chunks per row
            const int kc  = (c & 7) * 8;
            const float* src = B + (size_t)(n0 + row) * K_DIM + k0 + kc;
            f32x4 v0 = *(const f32x4*)(src);
            f32x4 v1 = *(const f32x4*)(src + 4);
            bf16x8 h;
            h[0] = (__bf16)v0[0]; h[1] = (__bf16)v0[1];
            h[2] = (__bf16)v0[2]; h[3] = (__bf16)v0[3];
            h[4] = (__bf16)v1[0]; h[5] = (__bf16)v1[1];
            h[6] = (__bf16)v1[2]; h[7] = (__bf16)v1[3];
            *(bf16x8*)&Bs[row * LDKB + kc] = h;
        }
        __syncthreads();   // compiler drains vmcnt (incl. gload_lds) + lgkmcnt

        #pragma unroll
        for (int ks = 0; ks < BK; ks += 32) {
            bf16x8 af[4], bfr[4];
            #pragma unroll
            for (int i = 0; i < 4; ++i)
                af[i] = *(const bf16x8*)&As[(wm + i * 16 + lrow) * BK + ks + lk];
            #pragma unroll
            for (int j = 0; j < 4; ++j)
                bfr[j] = *(const bf16x8*)&Bs[(wn + j * 16 + lrow) * LDKB + ks + lk];
            #pragma unroll
            for (int i = 0; i < 4; ++i)
                #pragma unroll
                for (int j = 0; j < 4; ++j)
                    acc[i][j] = __builtin_amdgcn_mfma_f32_16x16x32_bf16(
                        bfr[j], af[i], acc[i][j], 0, 0, 0);   // swapped: D.row -> n
        }
        __syncthreads();
    }

    // ---- epilogue: lane holds C[m = ..+lane&15][n = ..+(lane>>4)*4 + 0..3] -> f32x4
    const int lm = lane & 15;
    const int ln = (lane >> 4) * 4;
    #pragma unroll
    for (int i = 0; i < 4; ++i) {
        const size_t rowbase = (size_t)(m0 + wm + i * 16 + lm) * N_DIM;
        #pragma unroll
        for (int j = 0; j < 4; ++j) {
            float* dst = C + rowbase + (n0 + wn + j * 16 + ln);
            *(f32x4*)dst = acc[i][j];
        }
    }
}

extern "C" void kernel_launch(void* const* d_in, const int* in_sizes, int n_in,
                              void* d_out, int out_size, void* d_ws, size_t ws_size,
                              hipStream_t stream) {
    // setup_inputs order: inputs, indexes, features, mIoU, IoU
    const float* inputs   = (const float*)d_in[0];
    const float* features = (const float*)d_in[2];
    float* out = (float*)d_out;
    __bf16* Aw = (__bf16*)d_ws;          // needs 256 KB of workspace

    hipLaunchKernelGGL(cvt_inputs, dim3(M_DIM * K_DIM / (256 * 8)), dim3(256),
                       0, stream, inputs, Aw);

    dim3 grid(M_DIM / BM, N_DIM / BN);   // (4, 512)
    hipLaunchKernelGGL(hm_gemm_bt, grid, dim3(256), 0, stream,
                       Aw, features, out);
}

// Round 2
// 199.129 us; speedup vs baseline: 1.0622x; 1.0622x over previous
//
#include <hip/hip_runtime.h>
#include <hip/hip_bf16.h>

// out[512, 65536] = inputs[512,256] @ features[65536,256]^T  (fp32 in/out)
//
// v3: traffic-optimal blocking. grid.x = 1: each block owns a 128-col B panel
// for ALL of M, so features (64 MB) is read from HBM exactly once.
//   - B panel [128][256] fp32 -> bf16 staged to LDS ONCE per block (64 KB,
//     XOR-swizzled slots: conflict-free ds_read_b128).
//   - A pre-converted to bf16 ws, PRE-SWIZZLED per 128B k-block, so
//     global_load_lds (linear dest) lands it swizzled; reads apply same XOR.
//   - 4 m-passes x 4 k-steps; A tile 16 KB re-staged per step (L2-resident).
//   - LDS 80 KB -> 2 blocks/CU; 512 blocks = all co-resident, barriers overlap.

#define M_DIM 512
#define N_DIM 65536
#define K_DIM 256
#define BN 128
#define MP 128          // rows per m-pass
#define BK 64           // k-step for A staging

typedef __bf16 bf16x8 __attribute__((ext_vector_type(8)));
typedef float f32x4 __attribute__((ext_vector_type(4)));

// ---- kernel 1: inputs [512][256] fp32 -> bf16 ws, swizzled.
// ws elem layout: row*256 + blk*64 + (s ^ (row&7))*8 + e   (blk = k/64, s = (k%64)/8)
__global__ __launch_bounds__(256) void cvt_inputs(const float* __restrict__ A,
                                                  __bf16* __restrict__ Aw) {
    const int t   = blockIdx.x * 256 + threadIdx.x;   // 16384 threads
    const int row = t >> 5;
    const int grp = t & 31;
    const int blk = grp >> 3;
    const int s   = grp & 7;
    const float* src = A + (size_t)row * K_DIM + grp * 8;
    f32x4 v0 = *(const f32x4*)src;
    f32x4 v1 = *(const f32x4*)(src + 4);
    bf16x8 h;
    h[0] = (__bf16)v0[0]; h[1] = (__bf16)v0[1];
    h[2] = (__bf16)v0[2]; h[3] = (__bf16)v0[3];
    h[4] = (__bf16)v1[0]; h[5] = (__bf16)v1[1];
    h[6] = (__bf16)v1[2]; h[7] = (__bf16)v1[3];
    const int sst = s ^ (row & 7);
    *(bf16x8*)(Aw + (size_t)row * K_DIM + blk * 64 + sst * 8) = h;
}

static __device__ __forceinline__ void gload_lds16(const __bf16* g, __bf16* l) {
    __builtin_amdgcn_global_load_lds(
        (const __attribute__((address_space(1))) void*)g,
        (__attribute__((address_space(3))) void*)l, 16, 0, 0);
}

__global__ __launch_bounds__(256, 2) void hm_gemm_bt(
    const __bf16* __restrict__ Aw,  // [512][256] bf16 ws, pre-swizzled
    const float*  __restrict__ B,   // features [65536][256] fp32
    float* __restrict__ C)          // out [512][65536] fp32
{
    __shared__ __align__(16) __bf16 Bs[BN * K_DIM];  // 64 KB, full-K B panel
    __shared__ __align__(16) __bf16 As[MP * BK];     // 16 KB, per (mp,k0) tile

    const int tid  = threadIdx.x;
    const int lane = tid & 63;
    const int wave = tid >> 6;            // 4 waves, 2x2 grid of 64x64 subtiles
    const int wm   = (wave >> 1) * 64;
    const int wn   = (wave & 1) * 64;

    const int n0 = blockIdx.x * BN;       // grid = 512, one n-panel per block

    const int lrow = lane & 15;
    const int lk   = (lane >> 4) * 8;
    const int lx   = lrow & 7;            // per-lane XOR key (row&7 == lrow&7)

    // A-stage geometry: chunk ch (1 KB = 8 rows) -> lane l writes row 8ch+(l>>3),
    // slot l&7. Source = ws (pre-swizzled), linear 128 B per row-block.
    const int arow = lane >> 3;
    const int aslt = lane & 7;

    // ---- issue first A tile DMA (mp=0,k0=0), overlaps B staging below
    #pragma unroll
    for (int r = 0; r < 4; ++r) {
        const int ch = wave * 4 + r;
        gload_lds16(Aw + (size_t)(ch * 8 + arow) * K_DIM + aslt * 8,
                    As + ch * 512);
    }

    // ---- stage full B panel once: 128 rows x 256 k, fp32 -> bf16, swizzled
    #pragma unroll 4
    for (int it = 0; it < 16; ++it) {
        const int c   = it * 256 + tid;   // 0..4095 slots
        const int row = c >> 5;
        const int s   = c & 31;
        const float* src = B + (size_t)(n0 + row) * K_DIM + s * 8;
        f32x4 v0 = *(const f32x4*)(src);
        f32x4 v1 = *(const f32x4*)(src + 4);
        bf16x8 h;
        h[0] = (__bf16)v0[0]; h[1] = (__bf16)v0[1];
        h[2] = (__bf16)v0[2]; h[3] = (__bf16)v0[3];
        h[4] = (__bf16)v1[0]; h[5] = (__bf16)v1[1];
        h[6] = (__bf16)v1[2]; h[7] = (__bf16)v1[3];
        const int sst = s ^ (row & 7);
        *(bf16x8*)&Bs[row * K_DIM + sst * 8] = h;
    }

    for (int mp = 0; mp < M_DIM / MP; ++mp) {
        f32x4 acc[4][4];
        #pragma unroll
        for (int i = 0; i < 4; ++i)
            #pragma unroll
            for (int j = 0; j < 4; ++j)
                acc[i][j] = f32x4{0.f, 0.f, 0.f, 0.f};

        #pragma unroll
        for (int k0 = 0; k0 < K_DIM; k0 += BK) {
            if (mp != 0 || k0 != 0) {      // first tile already in flight
                #pragma unroll
                for (int r = 0; r < 4; ++r) {
                    const int ch = wave * 4 + r;
                    gload_lds16(Aw + (size_t)(mp * MP + ch * 8 + arow) * K_DIM
                                   + (k0 >> 6) * 64 + aslt * 8,
                                As + ch * 512);
                }
            }
            __syncthreads();   // drains gload_lds vmcnt + Bs lgkmcnt

            #pragma unroll
            for (int ks = 0; ks < BK; ks += 32) {
                bf16x8 af[4], bfr[4];
                #pragma unroll
                for (int i = 0; i < 4; ++i) {
                    const int row = wm + i * 16 + lrow;
                    const int pos = (((ks + lk) >> 3) ^ lx);
                    af[i] = *(const bf16x8*)&As[row * BK + pos * 8];
                }
                #pragma unroll
                for (int j = 0; j < 4; ++j) {
                    const int row = wn + j * 16 + lrow;
                    const int pos = (((k0 + ks + lk) >> 3) ^ lx);
                    bfr[j] = *(const bf16x8*)&Bs[row * K_DIM + pos * 8];
                }
                #pragma unroll
                for (int i = 0; i < 4; ++i)
                    #pragma unroll
                    for (int j = 0; j < 4; ++j)
                        acc[i][j] = __builtin_amdgcn_mfma_f32_16x16x32_bf16(
                            bfr[j], af[i], acc[i][j], 0, 0, 0);  // D.row -> n
            }
            __syncthreads();   // all reads done before next A stage overwrites
        }

        // ---- epilogue for this m-pass: lane holds C[m][n..n+3] -> f32x4
        const int lm = lane & 15;
        const int ln = (lane >> 4) * 4;
        #pragma unroll
        for (int i = 0; i < 4; ++i) {
            const size_t rowbase = (size_t)(mp * MP + wm + i * 16 + lm) * N_DIM;
            #pragma unroll
            for (int j = 0; j < 4; ++j) {
                float* dst = C + rowbase + (n0 + wn + j * 16 + ln);
                *(f32x4*)dst = acc[i][j];
            }
        }
    }
}

extern "C" void kernel_launch(void* const* d_in, const int* in_sizes, int n_in,
                              void* d_out, int out_size, void* d_ws, size_t ws_size,
                              hipStream_t stream) {
    // setup_inputs order: inputs, indexes, features, mIoU, IoU
    const float* inputs   = (const float*)d_in[0];
    const float* features = (const float*)d_in[2];
    float* out = (float*)d_out;
    __bf16* Aw = (__bf16*)d_ws;          // 256 KB of workspace

    hipLaunchKernelGGL(cvt_inputs, dim3(M_DIM * K_DIM / (256 * 8)), dim3(256),
                       0, stream, inputs, Aw);

    hipLaunchKernelGGL(hm_gemm_bt, dim3(N_DIM / BN), dim3(256), 0, stream,
                       Aw, features, out);
}